// Round 2
// baseline (968.002 us; speedup 1.0000x reference)
//
#include <hip/hip_runtime.h>

// ---------------------------------------------------------------------------
// Tensor_CSPNet forward, restructured:
//   out[b,o] = sum_h <G[o,h], log(V_h^T X[b,h] V_h + D_h)> + const[o]
// ReEig stages are provably no-ops (all eigenvalues >= 0.5 >> 1e-4).
// Eigensolve: one-sided Hestenes Jacobi, pair-per-lane in registers,
// 4 matrices per wave (16-lane rows, 11 active lanes each), DPP migration.
// R2: zero LDS (X/V/G reads are 16-lane broadcasts, L1/L2-hot), D loads
// directly into wL/wR, launch_bounds(64,4) for 16 waves/CU, 4-acc dots,
// NSWEEP 7->6.
// ---------------------------------------------------------------------------

#define WS_S     0                      // 484 floats  : S = rm^-1/2 @ bn^1/2
#define WS_CONST 484                    // 4 floats    : fc_w@conv_b + fc_b
#define WS_VT    512                    // 27*484      : Vt[h][j][k] = V_h[k][j]
#define WS_D     (512 + 27*484)         // 27*484      : D_h row-major (sym)
#define WS_G     (512 + 2*27*484)       // 4*27*528    : G[o][h], rows padded to 24
#define G_STRIDE 528
#define NSWEEP   6

static __device__ __forceinline__ float dpp_shl1(float x) { // lane m <- lane m+1 (within 16-row)
  return __int_as_float(__builtin_amdgcn_mov_dpp(__float_as_int(x), 0x101, 0xf, 0xf, true));
}
static __device__ __forceinline__ float dpp_shr1(float x) { // lane m <- lane m-1 (within 16-row)
  return __int_as_float(__builtin_amdgcn_mov_dpp(__float_as_int(x), 0x111, 0xf, 0xf, true));
}

// ---------------- prep1: S = rm^{-1/2} @ bn^{1/2} via Newton-Schulz ----------
__global__ void prep1_kernel(const float* __restrict__ rm, const float* __restrict__ bn,
                             const float* __restrict__ fc_w, const float* __restrict__ conv_b,
                             const float* __restrict__ fc_b, float* __restrict__ ws) {
  __shared__ float A[484], Y[484], Z[484], T[484], Y2[484], Z2[484], Gp[484], Gn[484];
  __shared__ float sh_th;
  int tid = threadIdx.x;
  for (int pass = 0; pass < 2; ++pass) {
    const float* src = (pass == 0) ? bn : rm;
    for (int idx = tid; idx < 484; idx += 256) A[idx] = src[idx];
    __syncthreads();
    if (tid == 0) { float tr = 0.f; for (int i = 0; i < 22; ++i) tr += A[i*23]; sh_th = 0.5f*tr; }
    __syncthreads();
    float th = sh_th;
    for (int idx = tid; idx < 484; idx += 256) {
      int i = idx/22, j = idx%22;
      Y[idx] = A[idx]/th;
      Z[idx] = (i==j) ? 1.0f : 0.0f;
    }
    __syncthreads();
    for (int it = 0; it < 16; ++it) {
      for (int idx = tid; idx < 484; idx += 256) {
        int i = idx/22, j = idx%22;
        float s = 0.f;
        for (int k = 0; k < 22; ++k) s += Z[i*22+k]*Y[k*22+j];
        T[idx] = ((i==j)?1.5f:0.0f) - 0.5f*s;
      }
      __syncthreads();
      for (int idx = tid; idx < 484; idx += 256) {
        int i = idx/22, j = idx%22;
        float sy = 0.f, sz = 0.f;
        for (int k = 0; k < 22; ++k) { sy += Y[i*22+k]*T[k*22+j]; sz += T[i*22+k]*Z[k*22+j]; }
        Y2[idx] = sy; Z2[idx] = sz;
      }
      __syncthreads();
      for (int idx = tid; idx < 484; idx += 256) { Y[idx] = Y2[idx]; Z[idx] = Z2[idx]; }
      __syncthreads();
    }
    float sth = sqrtf(th);
    for (int idx = tid; idx < 484; idx += 256) {
      if (pass == 0) Gp[idx] = Y[idx]*sth;   // bn^{1/2}
      else           Gn[idx] = Z[idx]/sth;   // rm^{-1/2}
    }
    __syncthreads();
  }
  for (int idx = tid; idx < 484; idx += 256) {
    int i = idx/22, j = idx%22;
    float s = 0.f;
    for (int k = 0; k < 22; ++k) s += Gn[i*22+k]*Gp[k*22+j];
    ws[WS_S + idx] = s;
  }
  if (tid < 4) {
    float s = 0.f;
    for (int c = 0; c < 48; ++c) s += fc_w[tid*48+c]*conv_b[c];
    ws[WS_CONST + tid] = s + fc_b[tid];
  }
}

// ---------------- prep2: per-h Vt, D, G ------------------------------------
__global__ void prep2_kernel(const float* __restrict__ W1, const float* __restrict__ W2,
                             const float* __restrict__ conv_w, const float* __restrict__ fc_w,
                             float* __restrict__ ws) {
  __shared__ float sW1[1024], sW2[704], sS[484], sU[704], sE[220], sG[1936];
  int h = blockIdx.x, tid = threadIdx.x;
  for (int idx = tid; idx < 1024; idx += 256) sW1[idx] = W1[h*1024+idx];
  for (int idx = tid; idx < 704;  idx += 256) sW2[idx] = W2[h*704+idx];
  for (int idx = tid; idx < 484;  idx += 256) sS[idx]  = ws[WS_S+idx];
  __syncthreads();
  // U = W1 @ W2  (32x22)
  for (int idx = tid; idx < 704; idx += 256) {
    int n = idx/22, j = idx%22;
    float s = 0.f;
    for (int k = 0; k < 32; ++k) s += sW1[n*32+k]*sW2[k*22+j];
    sU[idx] = s;
  }
  __syncthreads();
  // Vt[j][k] = (U_top @ S)[k][j]
  for (int idx = tid; idx < 484; idx += 256) {
    int k = idx/22, j = idx%22;
    float s = 0.f;
    for (int l = 0; l < 22; ++l) s += sU[k*22+l]*sS[l*22+j];
    ws[WS_VT + h*484 + j*22 + k] = s;
  }
  // E = U_bot @ S (10x22)
  for (int idx = tid; idx < 220; idx += 256) {
    int e = idx/22, j = idx%22;
    float s = 0.f;
    for (int l = 0; l < 22; ++l) s += sU[(22+e)*22+l]*sS[l*22+j];
    sE[idx] = s;
  }
  __syncthreads();
  // D = E^T E (22x22, symmetric)
  for (int idx = tid; idx < 484; idx += 256) {
    int i = idx/22, j = idx%22;
    float s = 0.f;
    for (int e = 0; e < 10; ++e) s += sE[e*22+i]*sE[e*22+j];
    ws[WS_D + h*484 + idx] = s;
  }
  // G[o][h] = sym( sum_c fc_w[o,c] * conv_w[c,0,wi, bi*484 + i*22+j] )
  int wi = h/9, bi = h%9;
  for (int idx = tid; idx < 1936; idx += 256) {
    int o = idx/484, r = idx%484;
    float s = 0.f;
    for (int c = 0; c < 48; ++c) s += fc_w[o*48+c]*conv_w[c*13068 + wi*4356 + bi*484 + r];
    sG[idx] = s;
  }
  __syncthreads();
  for (int idx = tid; idx < 1936; idx += 256) {
    int o = idx/484, r = idx%484, i = r/22, j = r%22;
    float v = 0.5f*(sG[o*484+i*22+j] + sG[o*484+j*22+i]);
    ws[WS_G + (o*27+h)*G_STRIDE + i*24 + j] = v;
  }
}

// ---------------- main: P4 build + one-sided Jacobi + projection -----------
// Zero LDS: X/V/G accesses are 16-lane broadcasts (same addr within group),
// served by L1/L2. Occupancy capped only by VGPRs: launch_bounds(64,4).
__global__ void __launch_bounds__(64, 4) main_kernel(const float* __restrict__ x,
                                                     const float* __restrict__ ws,
                                                     float* __restrict__ out) {
  const int lane = threadIdx.x;
  const int g = lane >> 4, m = lane & 15;
  const int mm = (m < 10) ? m : 10;          // lanes 11..15 mirror pair 10 (inert)
  const int id = blockIdx.x*4 + g;           // 13824 = 3456*4 exactly
  const int b = id / 27, h = id - b*27;

  // V column pair 2mm, 2mm+1 of this h (rows 2mm,2mm+1 of Vt; 44 contiguous)
  float vr[44];
  {
    const float4* vb = (const float4*)(ws + WS_VT + h*484 + mm*44);
    #pragma unroll
    for (int j = 0; j < 11; ++j) {
      float4 q = vb[j];
      vr[4*j+0]=q.x; vr[4*j+1]=q.y; vr[4*j+2]=q.z; vr[4*j+3]=q.w;
    }
  }
  // MM1: t[k] = sum_l X[k][l]*V[l][2mm(+1)]  (X read as group-broadcast)
  float tL[22], tR[22];
  {
    const float2* X2 = (const float2*)(x + (size_t)id * 484);
    #pragma unroll
    for (int k = 0; k < 22; ++k) {
      float aL = 0.f, aR = 0.f;
      #pragma unroll
      for (int c = 0; c < 11; ++c) {
        float2 xv = X2[11*k + c];
        aL += xv.x*vr[2*c]    + xv.y*vr[2*c+1];
        aR += xv.x*vr[22+2*c] + xv.y*vr[22+2*c+1];
      }
      tL[k] = aL; tR[k] = aR;
    }
  }
  // init w = D columns (rows 2mm,2mm+1 of symmetric D), loaded straight in
  float wL[22], wR[22];
  {
    const float4* d4 = (const float4*)(ws + WS_D + h*484 + mm*44);
    #pragma unroll
    for (int j = 0; j < 5; ++j) {
      float4 q = d4[j];
      wL[4*j+0]=q.x; wL[4*j+1]=q.y; wL[4*j+2]=q.z; wL[4*j+3]=q.w;
    }
    float2 q2 = ((const float2*)(ws + WS_D + h*484 + mm*44))[10];
    wL[20]=q2.x; wL[21]=q2.y;
    const float2* d2 = (const float2*)(ws + WS_D + h*484 + mm*44 + 22);
    #pragma unroll
    for (int j = 0; j < 11; ++j) {
      float2 q = d2[j];
      wR[2*j+0]=q.x; wR[2*j+1]=q.y;
    }
  }
  // MM2: w[i] += sum_k Vt[i][k]*t[k]  (Vt read as group-broadcast)
  {
    const float2* V2 = (const float2*)(ws + WS_VT + h*484);
    #pragma unroll
    for (int i = 0; i < 22; ++i) {
      float aL = wL[i], aR = wR[i];
      #pragma unroll
      for (int c = 0; c < 11; ++c) {
        float2 vv = V2[11*i + c];
        aL += vv.x*tL[2*c] + vv.y*tL[2*c+1];
        aR += vv.x*tR[2*c] + vv.y*tR[2*c+1];
      }
      wL[i] = aL; wR[i] = aR;
    }
  }

  // one-sided Jacobi (Hestenes), pair-per-lane, circle-method migration.
  // cycle: R0->R1->...->R10->L10->L9->...->L1->R0, L0 pinned. 21 rounds = full cycle.
  const bool is0 = (m == 0), is10 = (m == 10);
  #pragma unroll 1
  for (int sweep = 0; sweep < NSWEEP; ++sweep) {
    float n0=0.f,n1=0.f,n2=0.f,n3=0.f;
    #pragma unroll
    for (int i = 0; i < 22; ++i) {
      if ((i&3)==0) n0 += wL[i]*wL[i] + wR[i]*wR[i]*0.f; // keep separate below
    }
    // fresh norms each sweep (4-way ILP)
    float a0=0.f,a1=0.f,a2=0.f,a3=0.f,b0=0.f,b1=0.f,b2=0.f,b3=0.f;
    #pragma unroll
    for (int i = 0; i < 22; i += 2) {
      a0 += wL[i]*wL[i];   a1 += wL[i+1]*wL[i+1];
      b0 += wR[i]*wR[i];   b1 += wR[i+1]*wR[i+1];
    }
    float nL = a0 + a1, nR = b0 + b1;
    (void)n0;(void)n1;(void)n2;(void)n3;(void)a2;(void)a3;(void)b2;(void)b3;
    #pragma unroll 1
    for (int r = 0; r < 21; ++r) {
      float d0=0.f,d1=0.f,d2=0.f,d3=0.f;
      #pragma unroll
      for (int i = 0; i < 20; i += 4) {
        d0 += wL[i]*wR[i];     d1 += wL[i+1]*wR[i+1];
        d2 += wL[i+2]*wR[i+2]; d3 += wL[i+3]*wR[i+3];
      }
      d0 += wL[20]*wR[20]; d1 += wL[21]*wR[21];
      float d = (d0+d1)+(d2+d3);
      float ad  = fabsf(d);
      float tau = (nR - nL)*0.5f*__builtin_amdgcn_rcpf(d);
      float sq  = sqrtf(1.0f + tau*tau);
      float t   = copysignf(__builtin_amdgcn_rcpf(fabsf(tau) + sq), tau);
      float c   = __builtin_amdgcn_rsqf(1.0f + t*t);
      float s   = t*c;
      bool tiny = (ad < 1e-28f);
      c = tiny ? 1.0f : c;
      s = tiny ? 0.0f : s;
      float cc = c*c, ss = s*s, cs2 = 2.0f*c*s;
      float nLn = cc*nL - cs2*d + ss*nR;
      float nRn = ss*nL + cs2*d + cc*nR;
      #pragma unroll
      for (int i = 0; i < 22; ++i) {
        float nl = c*wL[i] - s*wR[i];
        float nr = s*wL[i] + c*wR[i];
        float tl = dpp_shl1(nl);              // lane m <- newL of m+1
        float tr = dpp_shr1(nr);              // lane m <- newR of m-1
        wL[i] = is0 ? nl : (is10 ? nr : tl);
        wR[i] = is0 ? tl : tr;
      }
      {
        float tl = dpp_shl1(nLn), tr = dpp_shr1(nRn);
        nL = is0 ? nLn : (is10 ? nRn : tl);
        nR = is0 ? tl : tr;
      }
    }
  }

  // log-eig coefficients: L = sum_j (log lam_j / lam_j^2) w_j w_j^T, lam^2 = ||w||^2
  float nL, nR;
  {
    float a0=0.f,a1=0.f,b0=0.f,b1=0.f;
    #pragma unroll
    for (int i = 0; i < 22; i += 2) {
      a0 += wL[i]*wL[i];   a1 += wL[i+1]*wL[i+1];
      b0 += wR[i]*wR[i];   b1 += wR[i+1]*wR[i+1];
    }
    nL = a0 + a1; nR = b0 + b1;
  }
  const float HALF_LN2 = 0.34657359f;        // 0.5*ln(2)
  float coefL = HALF_LN2*log2f(fmaxf(nL, 1e-8f))*__builtin_amdgcn_rcpf(nL);
  float coefR = HALF_LN2*log2f(fmaxf(nR, 1e-8f))*__builtin_amdgcn_rcpf(nR);

  // projection: out[b,o] += sum_cols coef * (w^T G[o,h] w)  (G rows broadcast)
  #pragma unroll 1
  for (int o = 0; o < 4; ++o) {
    const float* Gptr = ws + WS_G + (o*27+h)*G_STRIDE;
    float qL = 0.f, qR = 0.f;
    #pragma unroll
    for (int k = 0; k < 22; ++k) {
      float gr[22];
      const float4* g4 = (const float4*)(Gptr + k*24);
      #pragma unroll
      for (int j = 0; j < 5; ++j) {
        float4 q = g4[j];
        gr[4*j+0]=q.x; gr[4*j+1]=q.y; gr[4*j+2]=q.z; gr[4*j+3]=q.w;
      }
      {
        float2 q2 = ((const float2*)(Gptr + k*24))[10];
        gr[20]=q2.x; gr[21]=q2.y;
      }
      float s0=0.f,s1=0.f,r0=0.f,r1=0.f;
      #pragma unroll
      for (int i = 0; i < 22; i += 2) {
        s0 += gr[i]*wL[i];   s1 += gr[i+1]*wL[i+1];
        r0 += gr[i]*wR[i];   r1 += gr[i+1]*wR[i+1];
      }
      qL += wL[k]*(s0+s1); qR += wR[k]*(r0+r1);
    }
    float v = (m <= 10) ? (coefL*qL + coefR*qR) : 0.0f;
    v += __shfl_down(v, 8, 16);
    v += __shfl_down(v, 4, 16);
    v += __shfl_down(v, 2, 16);
    v += __shfl_down(v, 1, 16);
    if (m == 0) {
      if (h == 0) v += ws[WS_CONST + o];
      atomicAdd(out + b*4 + o, v);
    }
  }
}

extern "C" void kernel_launch(void* const* d_in, const int* in_sizes, int n_in,
                              void* d_out, int out_size, void* d_ws, size_t ws_size,
                              hipStream_t stream) {
  const float* x   = (const float*)d_in[0];
  const float* W1  = (const float*)d_in[1];
  const float* W2  = (const float*)d_in[2];
  const float* rm  = (const float*)d_in[3];
  const float* bn  = (const float*)d_in[4];
  const float* cw  = (const float*)d_in[5];
  const float* cb  = (const float*)d_in[6];
  const float* fw  = (const float*)d_in[7];
  const float* fb  = (const float*)d_in[8];
  float* out = (float*)d_out;
  float* ws  = (float*)d_ws;

  hipMemsetAsync(d_out, 0, (size_t)out_size*sizeof(float), stream);
  prep1_kernel<<<1, 256, 0, stream>>>(rm, bn, fw, cb, fb, ws);
  prep2_kernel<<<27, 256, 0, stream>>>(W1, W2, cw, fw, ws);
  main_kernel<<<3456, 64, 0, stream>>>(x, ws, out);
}

// Round 3
// 474.396 us; speedup vs baseline: 2.0405x; 2.0405x over previous
//
#include <hip/hip_runtime.h>

// ---------------------------------------------------------------------------
// Tensor_CSPNet forward, restructured:
//   out[b,o] = sum_h <G[o,h], log(V_h^T X[b,h] V_h + D_h)> + const[o]
// ReEig stages are provably no-ops (all eigenvalues >= 0.5 >> 1e-4).
// Eigensolve: one-sided Hestenes Jacobi, pair-per-lane in registers,
// 4 matrices per wave (16-lane rows, 11 active lanes each), DPP migration.
// R3: register-pressure restructure. Build phase streams rank-1 updates
// (no tL/tR[44]); projection streams G (no gr[22]); V stored row-major
// (stride 24) in addition to Vt. launch_bounds(64,3) -> cap 168 VGPR,
// >= 3 waves/SIMD, no spills (R2's (64,4) forced 64 VGPR -> 1.7 GB scratch).
// ---------------------------------------------------------------------------

#define WS_S     0                       // 484   : S = rm^-1/2 @ bn^1/2
#define WS_CONST 484                     // 4     : fc_w@conv_b + fc_b
#define WS_VT    512                     // 27*484: Vt[h][j][k] = V_h[k][j]
#define WS_V     (512 + 13068)           // 27*528: V[h][k][j], rows padded to 24
#define WS_D     (13580 + 14256)         // 27*484: D_h row-major (sym)
#define WS_G     (27836 + 13068)         // 4*27*528: G[o][h], rows padded to 24
#define G_STRIDE 528
#define V_STRIDE 528
#define NSWEEP   6

static __device__ __forceinline__ float dpp_shl1(float x) { // lane m <- lane m+1 (within 16-row)
  return __int_as_float(__builtin_amdgcn_mov_dpp(__float_as_int(x), 0x101, 0xf, 0xf, true));
}
static __device__ __forceinline__ float dpp_shr1(float x) { // lane m <- lane m-1 (within 16-row)
  return __int_as_float(__builtin_amdgcn_mov_dpp(__float_as_int(x), 0x111, 0xf, 0xf, true));
}

// ---------------- prep1: S = rm^{-1/2} @ bn^{1/2} via Newton-Schulz ----------
__global__ void prep1_kernel(const float* __restrict__ rm, const float* __restrict__ bn,
                             const float* __restrict__ fc_w, const float* __restrict__ conv_b,
                             const float* __restrict__ fc_b, float* __restrict__ ws) {
  __shared__ float A[484], Y[484], Z[484], T[484], Y2[484], Z2[484], Gp[484], Gn[484];
  __shared__ float sh_th;
  int tid = threadIdx.x;
  for (int pass = 0; pass < 2; ++pass) {
    const float* src = (pass == 0) ? bn : rm;
    for (int idx = tid; idx < 484; idx += 256) A[idx] = src[idx];
    __syncthreads();
    if (tid == 0) { float tr = 0.f; for (int i = 0; i < 22; ++i) tr += A[i*23]; sh_th = 0.5f*tr; }
    __syncthreads();
    float th = sh_th;
    for (int idx = tid; idx < 484; idx += 256) {
      int i = idx/22, j = idx%22;
      Y[idx] = A[idx]/th;
      Z[idx] = (i==j) ? 1.0f : 0.0f;
    }
    __syncthreads();
    for (int it = 0; it < 16; ++it) {
      for (int idx = tid; idx < 484; idx += 256) {
        int i = idx/22, j = idx%22;
        float s = 0.f;
        for (int k = 0; k < 22; ++k) s += Z[i*22+k]*Y[k*22+j];
        T[idx] = ((i==j)?1.5f:0.0f) - 0.5f*s;
      }
      __syncthreads();
      for (int idx = tid; idx < 484; idx += 256) {
        int i = idx/22, j = idx%22;
        float sy = 0.f, sz = 0.f;
        for (int k = 0; k < 22; ++k) { sy += Y[i*22+k]*T[k*22+j]; sz += T[i*22+k]*Z[k*22+j]; }
        Y2[idx] = sy; Z2[idx] = sz;
      }
      __syncthreads();
      for (int idx = tid; idx < 484; idx += 256) { Y[idx] = Y2[idx]; Z[idx] = Z2[idx]; }
      __syncthreads();
    }
    float sth = sqrtf(th);
    for (int idx = tid; idx < 484; idx += 256) {
      if (pass == 0) Gp[idx] = Y[idx]*sth;   // bn^{1/2}
      else           Gn[idx] = Z[idx]/sth;   // rm^{-1/2}
    }
    __syncthreads();
  }
  for (int idx = tid; idx < 484; idx += 256) {
    int i = idx/22, j = idx%22;
    float s = 0.f;
    for (int k = 0; k < 22; ++k) s += Gn[i*22+k]*Gp[k*22+j];
    ws[WS_S + idx] = s;
  }
  if (tid < 4) {
    float s = 0.f;
    for (int c = 0; c < 48; ++c) s += fc_w[tid*48+c]*conv_b[c];
    ws[WS_CONST + tid] = s + fc_b[tid];
  }
}

// ---------------- prep2: per-h Vt, V, D, G ---------------------------------
__global__ void prep2_kernel(const float* __restrict__ W1, const float* __restrict__ W2,
                             const float* __restrict__ conv_w, const float* __restrict__ fc_w,
                             float* __restrict__ ws) {
  __shared__ float sW1[1024], sW2[704], sS[484], sU[704], sE[220], sG[1936];
  int h = blockIdx.x, tid = threadIdx.x;
  for (int idx = tid; idx < 1024; idx += 256) sW1[idx] = W1[h*1024+idx];
  for (int idx = tid; idx < 704;  idx += 256) sW2[idx] = W2[h*704+idx];
  for (int idx = tid; idx < 484;  idx += 256) sS[idx]  = ws[WS_S+idx];
  __syncthreads();
  // U = W1 @ W2  (32x22)
  for (int idx = tid; idx < 704; idx += 256) {
    int n = idx/22, j = idx%22;
    float s = 0.f;
    for (int k = 0; k < 32; ++k) s += sW1[n*32+k]*sW2[k*22+j];
    sU[idx] = s;
  }
  __syncthreads();
  // V = U_top @ S (22x22): write both transposed (Vt, packed) and row-major (stride 24)
  for (int idx = tid; idx < 484; idx += 256) {
    int k = idx/22, j = idx%22;
    float s = 0.f;
    for (int l = 0; l < 22; ++l) s += sU[k*22+l]*sS[l*22+j];
    ws[WS_VT + h*484 + j*22 + k] = s;
    ws[WS_V  + h*V_STRIDE + k*24 + j] = s;
  }
  // E = U_bot @ S (10x22)
  for (int idx = tid; idx < 220; idx += 256) {
    int e = idx/22, j = idx%22;
    float s = 0.f;
    for (int l = 0; l < 22; ++l) s += sU[(22+e)*22+l]*sS[l*22+j];
    sE[idx] = s;
  }
  __syncthreads();
  // D = E^T E (22x22, symmetric)
  for (int idx = tid; idx < 484; idx += 256) {
    int i = idx/22, j = idx%22;
    float s = 0.f;
    for (int e = 0; e < 10; ++e) s += sE[e*22+i]*sE[e*22+j];
    ws[WS_D + h*484 + idx] = s;
  }
  // G[o][h] = sym( sum_c fc_w[o,c] * conv_w[c,0,wi, bi*484 + i*22+j] )
  int wi = h/9, bi = h%9;
  for (int idx = tid; idx < 1936; idx += 256) {
    int o = idx/484, r = idx%484;
    float s = 0.f;
    for (int c = 0; c < 48; ++c) s += fc_w[o*48+c]*conv_w[c*13068 + wi*4356 + bi*484 + r];
    sG[idx] = s;
  }
  __syncthreads();
  for (int idx = tid; idx < 1936; idx += 256) {
    int o = idx/484, r = idx%484, i = r/22, j = r%22;
    float v = 0.5f*(sG[o*484+i*22+j] + sG[o*484+j*22+i]);
    ws[WS_G + (o*27+h)*G_STRIDE + i*24 + j] = v;
  }
}

// ---------------- main: P4 build + one-sided Jacobi + projection -----------
// Zero LDS; X/V/D/G reads are 16-lane broadcasts served by L1/L2.
// launch_bounds(64,3): VGPR cap 168, peak live set ~110 floats -> no spill.
__global__ void __launch_bounds__(64, 3) main_kernel(const float* __restrict__ x,
                                                     const float* __restrict__ ws,
                                                     float* __restrict__ out) {
  const int lane = threadIdx.x;
  const int g = lane >> 4, m = lane & 15;
  const int mm = (m < 10) ? m : 10;          // lanes 11..15 mirror pair 10 (inert)
  const int id = blockIdx.x*4 + g;           // 13824 = 3456*4 exactly
  const int b = id / 27, h = id - b*27;

  // V column pair 2mm, 2mm+1 (rows 2mm,2mm+1 of Vt; 44 contiguous floats)
  float vr[44];
  {
    const float4* vb = (const float4*)(ws + WS_VT + h*484 + mm*44);
    #pragma unroll
    for (int j = 0; j < 11; ++j) {
      float4 q = vb[j];
      vr[4*j+0]=q.x; vr[4*j+1]=q.y; vr[4*j+2]=q.z; vr[4*j+3]=q.w;
    }
  }
  // init w = D rows 2mm, 2mm+1 (columns of symmetric D)
  float wL[22], wR[22];
  {
    const float4* d4 = (const float4*)(ws + WS_D + h*484 + mm*44);
    #pragma unroll
    for (int j = 0; j < 5; ++j) {
      float4 q = d4[j];
      wL[4*j+0]=q.x; wL[4*j+1]=q.y; wL[4*j+2]=q.z; wL[4*j+3]=q.w;
    }
    float2 q2 = ((const float2*)(ws + WS_D + h*484 + mm*44))[10];
    wL[20]=q2.x; wL[21]=q2.y;
    const float2* d2 = (const float2*)(ws + WS_D + h*484 + mm*44 + 22);
    #pragma unroll
    for (int j = 0; j < 11; ++j) {
      float2 q = d2[j];
      wR[2*j+0]=q.x; wR[2*j+1]=q.y;
    }
  }
  // streamed build: for each row k, t_k = <Xrow_k, v>, then w += V[k][:] * t_k
  {
    const float2* X2 = (const float2*)(x + (size_t)id * 484);
    const float* Vrow = ws + WS_V + h*V_STRIDE;
    #pragma unroll 2
    for (int k = 0; k < 22; ++k) {
      float a0=0.f,a1=0.f,b0=0.f,b1=0.f;
      #pragma unroll
      for (int c = 0; c < 11; ++c) {
        float2 xv = X2[11*k + c];
        a0 += xv.x*vr[2*c];    a1 += xv.y*vr[2*c+1];
        b0 += xv.x*vr[22+2*c]; b1 += xv.y*vr[22+2*c+1];
      }
      float tLk = a0+a1, tRk = b0+b1;
      const float4* vk = (const float4*)(Vrow + k*24);
      #pragma unroll
      for (int j = 0; j < 5; ++j) {
        float4 q = vk[j];
        wL[4*j+0] += q.x*tLk; wL[4*j+1] += q.y*tLk; wL[4*j+2] += q.z*tLk; wL[4*j+3] += q.w*tLk;
        wR[4*j+0] += q.x*tRk; wR[4*j+1] += q.y*tRk; wR[4*j+2] += q.z*tRk; wR[4*j+3] += q.w*tRk;
      }
      float2 q2 = ((const float2*)(Vrow + k*24))[10];
      wL[20] += q2.x*tLk; wL[21] += q2.y*tLk;
      wR[20] += q2.x*tRk; wR[21] += q2.y*tRk;
    }
  }

  // one-sided Jacobi (Hestenes), pair-per-lane, circle-method migration.
  // cycle: R0->R1->...->R10->L10->...->L1->R0, L0 pinned. 21 rounds = full cycle.
  const bool is0 = (m == 0), is10 = (m == 10);
  #pragma unroll 1
  for (int sweep = 0; sweep < NSWEEP; ++sweep) {
    float a0=0.f,a1=0.f,b0=0.f,b1=0.f;
    #pragma unroll
    for (int i = 0; i < 22; i += 2) {
      a0 += wL[i]*wL[i];   a1 += wL[i+1]*wL[i+1];
      b0 += wR[i]*wR[i];   b1 += wR[i+1]*wR[i+1];
    }
    float nL = a0 + a1, nR = b0 + b1;
    #pragma unroll 1
    for (int r = 0; r < 21; ++r) {
      float d0=0.f,d1=0.f,d2=0.f,d3=0.f;
      #pragma unroll
      for (int i = 0; i < 20; i += 4) {
        d0 += wL[i]*wR[i];     d1 += wL[i+1]*wR[i+1];
        d2 += wL[i+2]*wR[i+2]; d3 += wL[i+3]*wR[i+3];
      }
      d0 += wL[20]*wR[20]; d1 += wL[21]*wR[21];
      float d = (d0+d1)+(d2+d3);
      float ad  = fabsf(d);
      float tau = (nR - nL)*0.5f*__builtin_amdgcn_rcpf(d);
      float sq  = sqrtf(1.0f + tau*tau);
      float t   = copysignf(__builtin_amdgcn_rcpf(fabsf(tau) + sq), tau);
      float c   = __builtin_amdgcn_rsqf(1.0f + t*t);
      float s   = t*c;
      bool tiny = (ad < 1e-28f);
      c = tiny ? 1.0f : c;
      s = tiny ? 0.0f : s;
      float cc = c*c, ss = s*s, cs2 = 2.0f*c*s;
      float nLn = cc*nL - cs2*d + ss*nR;
      float nRn = ss*nL + cs2*d + cc*nR;
      #pragma unroll
      for (int i = 0; i < 22; ++i) {
        float nl = c*wL[i] - s*wR[i];
        float nr = s*wL[i] + c*wR[i];
        float tl = dpp_shl1(nl);              // lane m <- newL of m+1
        float tr = dpp_shr1(nr);              // lane m <- newR of m-1
        wL[i] = is0 ? nl : (is10 ? nr : tl);
        wR[i] = is0 ? tl : tr;
      }
      {
        float tl = dpp_shl1(nLn), tr = dpp_shr1(nRn);
        nL = is0 ? nLn : (is10 ? nRn : tl);
        nR = is0 ? tl : tr;
      }
    }
  }

  // log-eig coefficients: L = sum_j (log lam_j / lam_j^2) w_j w_j^T, lam^2 = ||w||^2
  float nL, nR;
  {
    float a0=0.f,a1=0.f,b0=0.f,b1=0.f;
    #pragma unroll
    for (int i = 0; i < 22; i += 2) {
      a0 += wL[i]*wL[i];   a1 += wL[i+1]*wL[i+1];
      b0 += wR[i]*wR[i];   b1 += wR[i+1]*wR[i+1];
    }
    nL = a0 + a1; nR = b0 + b1;
  }
  const float HALF_LN2 = 0.34657359f;        // 0.5*ln(2)
  float coefL = HALF_LN2*log2f(fmaxf(nL, 1e-8f))*__builtin_amdgcn_rcpf(nL);
  float coefR = HALF_LN2*log2f(fmaxf(nR, 1e-8f))*__builtin_amdgcn_rcpf(nR);

  // projection: out[b,o] += sum_cols coef * (w^T G[o,h] w), G streamed
  #pragma unroll 1
  for (int o = 0; o < 4; ++o) {
    const float* Gptr = ws + WS_G + (o*27+h)*G_STRIDE;
    float qL = 0.f, qR = 0.f;
    #pragma unroll
    for (int k = 0; k < 22; ++k) {
      const float4* g4 = (const float4*)(Gptr + k*24);
      float sa=0.f,sb=0.f,ra=0.f,rb=0.f;
      #pragma unroll
      for (int j = 0; j < 5; ++j) {
        float4 q = g4[j];
        sa += q.x*wL[4*j+0] + q.z*wL[4*j+2];
        sb += q.y*wL[4*j+1] + q.w*wL[4*j+3];
        ra += q.x*wR[4*j+0] + q.z*wR[4*j+2];
        rb += q.y*wR[4*j+1] + q.w*wR[4*j+3];
      }
      float2 q2 = ((const float2*)(Gptr + k*24))[10];
      sa += q2.x*wL[20]; sb += q2.y*wL[21];
      ra += q2.x*wR[20]; rb += q2.y*wR[21];
      qL += wL[k]*(sa+sb); qR += wR[k]*(ra+rb);
    }
    float v = (m <= 10) ? (coefL*qL + coefR*qR) : 0.0f;
    v += __shfl_down(v, 8, 16);
    v += __shfl_down(v, 4, 16);
    v += __shfl_down(v, 2, 16);
    v += __shfl_down(v, 1, 16);
    if (m == 0) {
      if (h == 0) v += ws[WS_CONST + o];
      atomicAdd(out + b*4 + o, v);
    }
  }
}

extern "C" void kernel_launch(void* const* d_in, const int* in_sizes, int n_in,
                              void* d_out, int out_size, void* d_ws, size_t ws_size,
                              hipStream_t stream) {
  const float* x   = (const float*)d_in[0];
  const float* W1  = (const float*)d_in[1];
  const float* W2  = (const float*)d_in[2];
  const float* rm  = (const float*)d_in[3];
  const float* bn  = (const float*)d_in[4];
  const float* cw  = (const float*)d_in[5];
  const float* cb  = (const float*)d_in[6];
  const float* fw  = (const float*)d_in[7];
  const float* fb  = (const float*)d_in[8];
  float* out = (float*)d_out;
  float* ws  = (float*)d_ws;

  hipMemsetAsync(d_out, 0, (size_t)out_size*sizeof(float), stream);
  prep1_kernel<<<1, 256, 0, stream>>>(rm, bn, fw, cb, fb, ws);
  prep2_kernel<<<27, 256, 0, stream>>>(W1, W2, cw, fw, ws);
  main_kernel<<<3456, 64, 0, stream>>>(x, ws, out);
}

// Round 4
// 410.475 us; speedup vs baseline: 2.3583x; 1.1557x over previous
//
#include <hip/hip_runtime.h>

// ---------------------------------------------------------------------------
// Tensor_CSPNet forward, restructured:
//   out[b,o] = sum_h <G[o,h], log(V_h^T X[b,h] V_h + D_h)> + const[o]
// ReEig stages are provably no-ops (all eigenvalues >= 0.5 >> 1e-4).
// Eigensolve: one-sided Hestenes Jacobi, pair-per-lane in registers,
// 4 matrices per wave (16-lane rows, 11 active lanes each), DPP migration.
// R4: packed fp32 (v_pk_fma_f32 via float2 ext_vector) in all hot loops;
// 5 sweeps + conditional 6th (converged check during sweep 5);
// prep1 runs both Newton-Schulz passes concurrently, 13 iters.
// ---------------------------------------------------------------------------

#define WS_S     0                       // 484   : S = rm^-1/2 @ bn^1/2
#define WS_CONST 484                     // 4     : fc_w@conv_b + fc_b
#define WS_VT    512                     // 27*484: Vt[h][j][k] = V_h[k][j]
#define WS_V     (512 + 13068)           // 27*528: V[h][k][j], rows padded to 24
#define WS_D     (13580 + 14256)         // 27*484: D_h row-major (sym)
#define WS_G     (27836 + 13068)         // 4*27*528: G[o][h], rows padded to 24
#define G_STRIDE 528
#define V_STRIDE 528

typedef float v2f __attribute__((ext_vector_type(2)));

static __device__ __forceinline__ float dpp_shl1(float x) { // lane m <- lane m+1 (within 16-row)
  return __int_as_float(__builtin_amdgcn_mov_dpp(__float_as_int(x), 0x101, 0xf, 0xf, true));
}
static __device__ __forceinline__ float dpp_shr1(float x) { // lane m <- lane m-1 (within 16-row)
  return __int_as_float(__builtin_amdgcn_mov_dpp(__float_as_int(x), 0x111, 0xf, 0xf, true));
}

// ---------------- prep1: S = rm^{-1/2} @ bn^{1/2}, both NS passes fused ------
__global__ void prep1_kernel(const float* __restrict__ rm, const float* __restrict__ bn,
                             const float* __restrict__ fc_w, const float* __restrict__ conv_b,
                             const float* __restrict__ fc_b, float* __restrict__ ws) {
  // slot 0 (elems 0..483): bn ; slot 1 (484..967): rm
  __shared__ float A[968], Y[968], Z[968], T[968], Y2[968], Z2[968];
  __shared__ float sh_th[2];
  int tid = threadIdx.x;
  for (int idx = tid; idx < 968; idx += 256)
    A[idx] = (idx < 484) ? bn[idx] : rm[idx - 484];
  __syncthreads();
  if (tid < 2) {
    float tr = 0.f;
    for (int i = 0; i < 22; ++i) tr += A[tid*484 + i*23];
    sh_th[tid] = 0.5f*tr;
  }
  __syncthreads();
  for (int idx = tid; idx < 968; idx += 256) {
    int p = (idx >= 484) ? 1 : 0, r = idx - p*484;
    int i = r/22, j = r%22;
    Y[idx] = A[idx]/sh_th[p];
    Z[idx] = (i==j) ? 1.0f : 0.0f;
  }
  __syncthreads();
  for (int it = 0; it < 13; ++it) {
    for (int idx = tid; idx < 968; idx += 256) {
      int p = (idx >= 484) ? 1 : 0, base = p*484, r = idx - base;
      int i = r/22, j = r%22;
      float s = 0.f;
      for (int k = 0; k < 22; ++k) s += Z[base + i*22+k]*Y[base + k*22+j];
      T[idx] = ((i==j)?1.5f:0.0f) - 0.5f*s;
    }
    __syncthreads();
    for (int idx = tid; idx < 968; idx += 256) {
      int p = (idx >= 484) ? 1 : 0, base = p*484, r = idx - base;
      int i = r/22, j = r%22;
      float sy = 0.f, sz = 0.f;
      for (int k = 0; k < 22; ++k) {
        sy += Y[base + i*22+k]*T[base + k*22+j];
        sz += T[base + i*22+k]*Z[base + k*22+j];
      }
      Y2[idx] = sy; Z2[idx] = sz;
    }
    __syncthreads();
    for (int idx = tid; idx < 968; idx += 256) { Y[idx] = Y2[idx]; Z[idx] = Z2[idx]; }
    __syncthreads();
  }
  // S = rm^{-1/2} @ bn^{1/2} = (sqrt(th0)/sqrt(th1)) * Z_rm @ Y_bn
  float scale = sqrtf(sh_th[0]/sh_th[1]);
  for (int idx = tid; idx < 484; idx += 256) {
    int i = idx/22, j = idx%22;
    float s = 0.f;
    for (int k = 0; k < 22; ++k) s += Z[484 + i*22+k]*Y[k*22+j];
    ws[WS_S + idx] = s*scale;
  }
  if (tid < 4) {
    float s = 0.f;
    for (int c = 0; c < 48; ++c) s += fc_w[tid*48+c]*conv_b[c];
    ws[WS_CONST + tid] = s + fc_b[tid];
  }
}

// ---------------- prep2: per-h Vt, V, D, G ---------------------------------
__global__ void prep2_kernel(const float* __restrict__ W1, const float* __restrict__ W2,
                             const float* __restrict__ conv_w, const float* __restrict__ fc_w,
                             float* __restrict__ ws) {
  __shared__ float sW1[1024], sW2[704], sS[484], sU[704], sE[220], sG[1936];
  int h = blockIdx.x, tid = threadIdx.x;
  for (int idx = tid; idx < 1024; idx += 256) sW1[idx] = W1[h*1024+idx];
  for (int idx = tid; idx < 704;  idx += 256) sW2[idx] = W2[h*704+idx];
  for (int idx = tid; idx < 484;  idx += 256) sS[idx]  = ws[WS_S+idx];
  __syncthreads();
  // U = W1 @ W2  (32x22)
  for (int idx = tid; idx < 704; idx += 256) {
    int n = idx/22, j = idx%22;
    float s = 0.f;
    for (int k = 0; k < 32; ++k) s += sW1[n*32+k]*sW2[k*22+j];
    sU[idx] = s;
  }
  __syncthreads();
  // V = U_top @ S (22x22): write transposed (Vt, packed) and row-major (stride 24)
  for (int idx = tid; idx < 484; idx += 256) {
    int k = idx/22, j = idx%22;
    float s = 0.f;
    for (int l = 0; l < 22; ++l) s += sU[k*22+l]*sS[l*22+j];
    ws[WS_VT + h*484 + j*22 + k] = s;
    ws[WS_V  + h*V_STRIDE + k*24 + j] = s;
  }
  // E = U_bot @ S (10x22)
  for (int idx = tid; idx < 220; idx += 256) {
    int e = idx/22, j = idx%22;
    float s = 0.f;
    for (int l = 0; l < 22; ++l) s += sU[(22+e)*22+l]*sS[l*22+j];
    sE[idx] = s;
  }
  __syncthreads();
  // D = E^T E (22x22, symmetric)
  for (int idx = tid; idx < 484; idx += 256) {
    int i = idx/22, j = idx%22;
    float s = 0.f;
    for (int e = 0; e < 10; ++e) s += sE[e*22+i]*sE[e*22+j];
    ws[WS_D + h*484 + idx] = s;
  }
  // G[o][h] = sym( sum_c fc_w[o,c] * conv_w[c,0,wi, bi*484 + i*22+j] )
  int wi = h/9, bi = h%9;
  for (int idx = tid; idx < 1936; idx += 256) {
    int o = idx/484, r = idx%484;
    float s = 0.f;
    for (int c = 0; c < 48; ++c) s += fc_w[o*48+c]*conv_w[c*13068 + wi*4356 + bi*484 + r];
    sG[idx] = s;
  }
  __syncthreads();
  for (int idx = tid; idx < 1936; idx += 256) {
    int o = idx/484, r = idx%484, i = r/22, j = r%22;
    float v = 0.5f*(sG[o*484+i*22+j] + sG[o*484+j*22+i]);
    ws[WS_G + (o*27+h)*G_STRIDE + i*24 + j] = v;
  }
}

// ---------------- main: P4 build + one-sided Jacobi + projection -----------
// Zero LDS; X/V/D/G reads are 16-lane broadcasts served by L1/L2.
// Packed fp32 arithmetic; migration stays scalar DPP/cndmask.
__global__ void __launch_bounds__(64, 3) main_kernel(const float* __restrict__ x,
                                                     const float* __restrict__ ws,
                                                     float* __restrict__ out) {
  const int lane = threadIdx.x;
  const int g = lane >> 4, m = lane & 15;
  const int mm = (m < 10) ? m : 10;          // lanes 11..15 mirror pair 10 (inert)
  const int id = blockIdx.x*4 + g;           // 13824 = 3456*4 exactly
  const int b = id / 27, h = id - b*27;

  // V column pair 2mm, 2mm+1 (rows 2mm,2mm+1 of Vt; 44 contiguous floats)
  v2f vl[11], vrr[11];
  {
    const v2f* vb = (const v2f*)(ws + WS_VT + h*484 + mm*44);
    #pragma unroll
    for (int j = 0; j < 11; ++j) { vl[j] = vb[j]; vrr[j] = vb[11+j]; }
  }
  // init w = D rows 2mm, 2mm+1 (columns of symmetric D)
  v2f wl[11], wr[11];
  {
    const v2f* d2 = (const v2f*)(ws + WS_D + h*484 + mm*44);
    #pragma unroll
    for (int j = 0; j < 11; ++j) { wl[j] = d2[j]; wr[j] = d2[11+j]; }
  }
  // streamed build: for each row k, t_k = <Xrow_k, v>, then w += V[k][:] * t_k
  {
    const v2f* X2 = (const v2f*)(x + (size_t)id * 484);
    const float* Vrow = ws + WS_V + h*V_STRIDE;
    #pragma unroll 2
    for (int k = 0; k < 22; ++k) {
      v2f aL = (v2f)(0.f), aR = (v2f)(0.f);
      #pragma unroll
      for (int c = 0; c < 11; ++c) {
        v2f xv = X2[11*k + c];
        aL += xv*vl[c];
        aR += xv*vrr[c];
      }
      float tLk = aL.x + aL.y, tRk = aR.x + aR.y;
      const v2f* vk = (const v2f*)(Vrow + k*24);
      #pragma unroll
      for (int j = 0; j < 11; ++j) {
        v2f q = vk[j];
        wl[j] += q*tLk;
        wr[j] += q*tRk;
      }
    }
  }

  // one-sided Jacobi (Hestenes), pair-per-lane, circle-method migration.
  // cycle: R0->R1->...->R10->L10->...->L1->R0, L0 pinned. 21 rounds = full cycle.
  // 5 sweeps always; 6th only if not converged (checked during sweep 5).
  const bool is0 = (m == 0), is10 = (m == 10);
  int okmask = 1;
  #pragma unroll 1
  for (int sweep = 0; sweep < 6; ++sweep) {
    if (sweep == 5 && __all(okmask)) break;
    okmask = 1;
    v2f na = (v2f)(0.f), nb = (v2f)(0.f);
    #pragma unroll
    for (int i = 0; i < 11; ++i) { na += wl[i]*wl[i]; nb += wr[i]*wr[i]; }
    float nL = na.x + na.y, nR = nb.x + nb.y;
    #pragma unroll 1
    for (int r = 0; r < 21; ++r) {
      v2f da = (v2f)(0.f), db = (v2f)(0.f);
      #pragma unroll
      for (int i = 0; i < 10; i += 2) { da += wl[i]*wr[i]; db += wl[i+1]*wr[i+1]; }
      da += wl[10]*wr[10];
      float d = (da.x + da.y) + (db.x + db.y);
      okmask &= (d*d <= 1e-5f*(nL*nR));
      float ad  = fabsf(d);
      float tau = (nR - nL)*0.5f*__builtin_amdgcn_rcpf(d);
      float sq  = sqrtf(1.0f + tau*tau);
      float t   = copysignf(__builtin_amdgcn_rcpf(fabsf(tau) + sq), tau);
      float c   = __builtin_amdgcn_rsqf(1.0f + t*t);
      float s   = t*c;
      bool tiny = (ad < 1e-28f);
      c = tiny ? 1.0f : c;
      s = tiny ? 0.0f : s;
      float cc = c*c, ss = s*s, cs2 = 2.0f*c*s;
      float nLn = cc*nL - cs2*d + ss*nR;
      float nRn = ss*nL + cs2*d + cc*nR;
      v2f cv = (v2f)(c), sv = (v2f)(s);
      #pragma unroll
      for (int i = 0; i < 11; ++i) {
        v2f nl = cv*wl[i] - sv*wr[i];
        v2f nr = sv*wl[i] + cv*wr[i];
        float tlx = dpp_shl1(nl.x), tly = dpp_shl1(nl.y);
        float trx = dpp_shr1(nr.x), trY = dpp_shr1(nr.y);
        wl[i].x = is0 ? nl.x : (is10 ? nr.x : tlx);
        wl[i].y = is0 ? nl.y : (is10 ? nr.y : tly);
        wr[i].x = is0 ? tlx : trx;
        wr[i].y = is0 ? tly : trY;
      }
      {
        float tl = dpp_shl1(nLn), tr = dpp_shr1(nRn);
        nL = is0 ? nLn : (is10 ? nRn : tl);
        nR = is0 ? tl : tr;
      }
    }
  }

  // log-eig coefficients: L = sum_j (log lam_j / lam_j^2) w_j w_j^T, lam^2 = ||w||^2
  float nL, nR;
  {
    v2f na = (v2f)(0.f), nb = (v2f)(0.f);
    #pragma unroll
    for (int i = 0; i < 11; ++i) { na += wl[i]*wl[i]; nb += wr[i]*wr[i]; }
    nL = na.x + na.y; nR = nb.x + nb.y;
  }
  const float HALF_LN2 = 0.34657359f;        // 0.5*ln(2)
  float coefL = HALF_LN2*log2f(fmaxf(nL, 1e-8f))*__builtin_amdgcn_rcpf(nL);
  float coefR = HALF_LN2*log2f(fmaxf(nR, 1e-8f))*__builtin_amdgcn_rcpf(nR);

  // projection: out[b,o] += sum_cols coef * (w^T G[o,h] w), G streamed
  #pragma unroll 1
  for (int o = 0; o < 4; ++o) {
    const float* Gptr = ws + WS_G + (o*27+h)*G_STRIDE;
    float qL = 0.f, qR = 0.f;
    #pragma unroll
    for (int k = 0; k < 22; ++k) {
      const v2f* g2 = (const v2f*)(Gptr + k*24);
      v2f sa = (v2f)(0.f), ra = (v2f)(0.f);
      #pragma unroll
      for (int j = 0; j < 11; ++j) {
        v2f q = g2[j];
        sa += q*wl[j];
        ra += q*wr[j];
      }
      float wLk = wl[k>>1][k&1], wRk = wr[k>>1][k&1];
      qL += wLk*(sa.x + sa.y);
      qR += wRk*(ra.x + ra.y);
    }
    float v = (m <= 10) ? (coefL*qL + coefR*qR) : 0.0f;
    v += __shfl_down(v, 8, 16);
    v += __shfl_down(v, 4, 16);
    v += __shfl_down(v, 2, 16);
    v += __shfl_down(v, 1, 16);
    if (m == 0) {
      if (h == 0) v += ws[WS_CONST + o];
      atomicAdd(out + b*4 + o, v);
    }
  }
}

extern "C" void kernel_launch(void* const* d_in, const int* in_sizes, int n_in,
                              void* d_out, int out_size, void* d_ws, size_t ws_size,
                              hipStream_t stream) {
  const float* x   = (const float*)d_in[0];
  const float* W1  = (const float*)d_in[1];
  const float* W2  = (const float*)d_in[2];
  const float* rm  = (const float*)d_in[3];
  const float* bn  = (const float*)d_in[4];
  const float* cw  = (const float*)d_in[5];
  const float* cb  = (const float*)d_in[6];
  const float* fw  = (const float*)d_in[7];
  const float* fb  = (const float*)d_in[8];
  float* out = (float*)d_out;
  float* ws  = (float*)d_ws;

  hipMemsetAsync(d_out, 0, (size_t)out_size*sizeof(float), stream);
  prep1_kernel<<<1, 256, 0, stream>>>(rm, bn, fw, cb, fb, ws);
  prep2_kernel<<<27, 256, 0, stream>>>(W1, W2, cw, fw, ws);
  main_kernel<<<3456, 64, 0, stream>>>(x, ws, out);
}

// Round 6
// 386.876 us; speedup vs baseline: 2.5021x; 1.0610x over previous
//
#include <hip/hip_runtime.h>

// ---------------------------------------------------------------------------
// Tensor_CSPNet forward, restructured:
//   out[b,o] = sum_h <G[o,h], log(V_h^T X[b,h] V_h + D_h)> + const[o]
// ReEig stages are provably no-ops (all eigenvalues >= 0.5 >> 1e-4).
// Eigensolve: one-sided Hestenes Jacobi, pair-per-lane in registers,
// 4 matrices per wave (16-lane rows, 11 active lanes each), DPP migration.
// R6: fix prep S-computation offset (Z slot1 is Z[484+..], R5 read the T
// array => S scaled by 1/sqrt(11) => absmax 0.33). Keeps R5's wave-uniform
// h (scalar-pipe V/D/G loads), adaptive 4-sweep exit, single fused prep.
// ---------------------------------------------------------------------------

#define WS_CONST 484                     // 4     : fc_w@conv_b + fc_b
#define WS_VT    512                     // 27*484: Vt[h][j][k] = V_h[k][j]
#define WS_V     (512 + 13068)           // 27*528: V[h][k][j], rows padded to 24
#define WS_D     (13580 + 14256)         // 27*484: D_h row-major (sym)
#define WS_G     (27836 + 13068)         // 4*27*528: G[o][h], rows padded to 24
#define G_STRIDE 528
#define V_STRIDE 528

typedef float v2f __attribute__((ext_vector_type(2)));

static __device__ __forceinline__ float dpp_shl1(float x) { // lane m <- lane m+1 (within 16-row)
  return __int_as_float(__builtin_amdgcn_mov_dpp(__float_as_int(x), 0x101, 0xf, 0xf, true));
}
static __device__ __forceinline__ float dpp_shr1(float x) { // lane m <- lane m-1 (within 16-row)
  return __int_as_float(__builtin_amdgcn_mov_dpp(__float_as_int(x), 0x111, 0xf, 0xf, true));
}

// ---------------- fused prep: NS(rm,bn) -> S -> per-h Vt, V, D, G ----------
__global__ void prep_kernel(const float* __restrict__ rm, const float* __restrict__ bn,
                            const float* __restrict__ W1, const float* __restrict__ W2,
                            const float* __restrict__ conv_w, const float* __restrict__ fc_w,
                            const float* __restrict__ conv_b, const float* __restrict__ fc_b,
                            float* __restrict__ ws) {
  __shared__ float buf[5808];
  __shared__ float sh_th[2];
  int tid = threadIdx.x, h = blockIdx.x;
  // ---- phase 1: coupled Newton-Schulz for bn^{1/2} (slot0) and rm^{-1/2} (slot1)
  {
    float* A  = buf;        float* Y  = buf + 968;  float* Z  = buf + 1936;
    float* T  = buf + 2904; float* Y2 = buf + 3872; float* Z2 = buf + 4840;
    for (int idx = tid; idx < 968; idx += 256)
      A[idx] = (idx < 484) ? bn[idx] : rm[idx - 484];
    __syncthreads();
    if (tid < 2) {
      float tr = 0.f;
      for (int i = 0; i < 22; ++i) tr += A[tid*484 + i*23];
      sh_th[tid] = 0.5f*tr;
    }
    __syncthreads();
    for (int idx = tid; idx < 968; idx += 256) {
      int p = (idx >= 484) ? 1 : 0, r = idx - p*484;
      int i = r/22, j = r%22;
      Y[idx] = A[idx]/sh_th[p];
      Z[idx] = (i==j) ? 1.0f : 0.0f;
    }
    __syncthreads();
    for (int it = 0; it < 13; ++it) {
      for (int idx = tid; idx < 968; idx += 256) {
        int p = (idx >= 484) ? 1 : 0, base = p*484, r = idx - base;
        int i = r/22, j = r%22;
        float s = 0.f;
        for (int k = 0; k < 22; ++k) s += Z[base + i*22+k]*Y[base + k*22+j];
        T[idx] = ((i==j)?1.5f:0.0f) - 0.5f*s;
      }
      __syncthreads();
      for (int idx = tid; idx < 968; idx += 256) {
        int p = (idx >= 484) ? 1 : 0, base = p*484, r = idx - base;
        int i = r/22, j = r%22;
        float sy = 0.f, sz = 0.f;
        for (int k = 0; k < 22; ++k) {
          sy += Y[base + i*22+k]*T[base + k*22+j];
          sz += T[base + i*22+k]*Z[base + k*22+j];
        }
        Y2[idx] = sy; Z2[idx] = sz;
      }
      __syncthreads();
      for (int idx = tid; idx < 968; idx += 256) { Y[idx] = Y2[idx]; Z[idx] = Z2[idx]; }
      __syncthreads();
    }
    // S = rm^{-1/2} @ bn^{1/2} = sqrt(th0/th1) * Z_rm @ Y_bn  -> buf[0..484)
    // Z_rm = Z slot1 = Z[484 + ...]  (R5 bug: read Z[968+484+..] = T array)
    float scale = sqrtf(sh_th[0]/sh_th[1]);
    for (int idx = tid; idx < 484; idx += 256) {
      int i = idx/22, j = idx%22;
      float s = 0.f;
      for (int k = 0; k < 22; ++k) s += Z[484 + i*22+k]*Y[k*22+j]; // Z slot1, Y slot0
      buf[idx] = s*scale;   // A region, dead
    }
    __syncthreads();
  }
  // ---- phase 2: per-h weights (aliases over buf; phase-1 arrays dead)
  float* sS  = buf;           // 484
  float* sW1 = buf + 484;     // 1024
  float* sW2 = buf + 1508;    // 704
  float* sU  = buf + 2212;    // 704
  float* sE  = buf + 2916;    // 220
  float* sG  = buf + 3136;    // 1936
  for (int idx = tid; idx < 1024; idx += 256) sW1[idx] = W1[h*1024+idx];
  for (int idx = tid; idx < 704;  idx += 256) sW2[idx] = W2[h*704+idx];
  __syncthreads();
  // U = W1 @ W2  (32x22)
  for (int idx = tid; idx < 704; idx += 256) {
    int n = idx/22, j = idx%22;
    float s = 0.f;
    for (int k = 0; k < 32; ++k) s += sW1[n*32+k]*sW2[k*22+j];
    sU[idx] = s;
  }
  __syncthreads();
  // V = U_top @ S (22x22): write transposed (Vt, packed) and row-major (stride 24)
  for (int idx = tid; idx < 484; idx += 256) {
    int k = idx/22, j = idx%22;
    float s = 0.f;
    for (int l = 0; l < 22; ++l) s += sU[k*22+l]*sS[l*22+j];
    ws[WS_VT + h*484 + j*22 + k] = s;
    ws[WS_V  + h*V_STRIDE + k*24 + j] = s;
  }
  // E = U_bot @ S (10x22)
  for (int idx = tid; idx < 220; idx += 256) {
    int e = idx/22, j = idx%22;
    float s = 0.f;
    for (int l = 0; l < 22; ++l) s += sU[(22+e)*22+l]*sS[l*22+j];
    sE[idx] = s;
  }
  __syncthreads();
  // D = E^T E (22x22, symmetric)
  for (int idx = tid; idx < 484; idx += 256) {
    int i = idx/22, j = idx%22;
    float s = 0.f;
    for (int e = 0; e < 10; ++e) s += sE[e*22+i]*sE[e*22+j];
    ws[WS_D + h*484 + idx] = s;
  }
  // G[o][h] = sym( sum_c fc_w[o,c] * conv_w[c,0,wi, bi*484 + i*22+j] )
  int wi = h/9, bi = h%9;
  for (int idx = tid; idx < 1936; idx += 256) {
    int o = idx/484, r = idx%484;
    float s = 0.f;
    for (int c = 0; c < 48; ++c) s += fc_w[o*48+c]*conv_w[c*13068 + wi*4356 + bi*484 + r];
    sG[idx] = s;
  }
  __syncthreads();
  for (int idx = tid; idx < 1936; idx += 256) {
    int o = idx/484, r = idx%484, i = r/22, j = r%22;
    float v = 0.5f*(sG[o*484+i*22+j] + sG[o*484+j*22+i]);
    ws[WS_G + (o*27+h)*G_STRIDE + i*24 + j] = v;
  }
  if (h == 0 && tid < 4) {
    float s = 0.f;
    for (int c = 0; c < 48; ++c) s += fc_w[tid*48+c]*conv_b[c];
    ws[WS_CONST + tid] = s + fc_b[tid];
  }
}

// ---------------- main: P4 build + one-sided Jacobi + projection -----------
// h is wave-uniform -> V/D/G base pointers uniform -> scalar loads (SMEM).
// Zero LDS; per-lane X/Vt/D reads are 16-lane broadcasts served by L1/L2.
__global__ void __launch_bounds__(64, 3) main_kernel(const float* __restrict__ x,
                                                     const float* __restrict__ ws,
                                                     float* __restrict__ out) {
  const int lane = threadIdx.x;
  const int g = lane >> 4, m = lane & 15;
  const int mm = (m < 10) ? m : 10;          // lanes 11..15 mirror pair 10 (inert)
  const int h  = blockIdx.x % 27;            // wave-uniform
  const int bq = blockIdx.x / 27;            // 0..127
  const int b  = bq*4 + g;
  const int id = b*27 + h;                   // matrix index in x

  // V column pair 2mm, 2mm+1 (rows 2mm,2mm+1 of Vt; 44 contiguous floats)
  v2f vl[11], vrr[11];
  {
    const v2f* vb = (const v2f*)(ws + WS_VT + h*484 + mm*44);
    #pragma unroll
    for (int j = 0; j < 11; ++j) { vl[j] = vb[j]; vrr[j] = vb[11+j]; }
  }
  // init w = D rows 2mm, 2mm+1 (columns of symmetric D)
  v2f wl[11], wr[11];
  {
    const v2f* d2 = (const v2f*)(ws + WS_D + h*484 + mm*44);
    #pragma unroll
    for (int j = 0; j < 11; ++j) { wl[j] = d2[j]; wr[j] = d2[11+j]; }
  }
  // streamed build: for each row k, t_k = <Xrow_k, v>, then w += V[k][:] * t_k
  // Vrow is wave-uniform -> scalar loads feeding pk FMAs.
  {
    const v2f* X2 = (const v2f*)(x + (size_t)id * 484);
    const float* Vrow = ws + WS_V + h*V_STRIDE;
    #pragma unroll 2
    for (int k = 0; k < 22; ++k) {
      v2f aL = (v2f)(0.f), aR = (v2f)(0.f);
      #pragma unroll
      for (int c = 0; c < 11; ++c) {
        v2f xv = X2[11*k + c];
        aL += xv*vl[c];
        aR += xv*vrr[c];
      }
      float tLk = aL.x + aL.y, tRk = aR.x + aR.y;
      const v2f* vk = (const v2f*)(Vrow + k*24);
      #pragma unroll
      for (int j = 0; j < 11; ++j) {
        v2f q = vk[j];
        wl[j] += q*tLk;
        wr[j] += q*tRk;
      }
    }
  }

  // one-sided Jacobi (Hestenes), pair-per-lane, circle-method migration.
  // cycle: R0->R1->...->R10->L10->...->L1->R0, L0 pinned. 21 rounds = full cycle.
  // Adaptive: minimum 4 sweeps, exit when previous sweep was fully converged.
  const bool is0 = (m == 0), is10 = (m == 10);
  int okmask = 0;
  #pragma unroll 1
  for (int sweep = 0; sweep < 6; ++sweep) {
    if (sweep >= 4 && __all(okmask)) break;
    okmask = 1;
    v2f na = (v2f)(0.f), nb = (v2f)(0.f);
    #pragma unroll
    for (int i = 0; i < 11; ++i) { na += wl[i]*wl[i]; nb += wr[i]*wr[i]; }
    float nL = na.x + na.y, nR = nb.x + nb.y;
    #pragma unroll 1
    for (int r = 0; r < 21; ++r) {
      v2f da = (v2f)(0.f), db = (v2f)(0.f);
      #pragma unroll
      for (int i = 0; i < 10; i += 2) { da += wl[i]*wr[i]; db += wl[i+1]*wr[i+1]; }
      da += wl[10]*wr[10];
      float d = (da.x + da.y) + (db.x + db.y);
      okmask &= (d*d <= 1e-5f*(nL*nR));
      float ad  = fabsf(d);
      float tau = (nR - nL)*0.5f*__builtin_amdgcn_rcpf(d);
      float sq  = sqrtf(1.0f + tau*tau);
      float t   = copysignf(__builtin_amdgcn_rcpf(fabsf(tau) + sq), tau);
      float c   = __builtin_amdgcn_rsqf(1.0f + t*t);
      float s   = t*c;
      bool tiny = (ad < 1e-28f);
      c = tiny ? 1.0f : c;
      s = tiny ? 0.0f : s;
      float cc = c*c, ss = s*s, cs2 = 2.0f*c*s;
      float nLn = cc*nL - cs2*d + ss*nR;
      float nRn = ss*nL + cs2*d + cc*nR;
      v2f cv = (v2f)(c), sv = (v2f)(s);
      #pragma unroll
      for (int i = 0; i < 11; ++i) {
        v2f nl = cv*wl[i] - sv*wr[i];
        v2f nr = sv*wl[i] + cv*wr[i];
        float tlx = dpp_shl1(nl.x), tly = dpp_shl1(nl.y);
        float trx = dpp_shr1(nr.x), trY = dpp_shr1(nr.y);
        wl[i].x = is0 ? nl.x : (is10 ? nr.x : tlx);
        wl[i].y = is0 ? nl.y : (is10 ? nr.y : tly);
        wr[i].x = is0 ? tlx : trx;
        wr[i].y = is0 ? tly : trY;
      }
      {
        float tl = dpp_shl1(nLn), tr = dpp_shr1(nRn);
        nL = is0 ? nLn : (is10 ? nRn : tl);
        nR = is0 ? tl : tr;
      }
    }
  }

  // log-eig coefficients: L = sum_j (log lam_j / lam_j^2) w_j w_j^T, lam^2 = ||w||^2
  float nL, nR;
  {
    v2f na = (v2f)(0.f), nb = (v2f)(0.f);
    #pragma unroll
    for (int i = 0; i < 11; ++i) { na += wl[i]*wl[i]; nb += wr[i]*wr[i]; }
    nL = na.x + na.y; nR = nb.x + nb.y;
  }
  const float HALF_LN2 = 0.34657359f;        // 0.5*ln(2)
  float coefL = HALF_LN2*log2f(fmaxf(nL, 1e-8f))*__builtin_amdgcn_rcpf(nL);
  float coefR = HALF_LN2*log2f(fmaxf(nR, 1e-8f))*__builtin_amdgcn_rcpf(nR);

  // projection: out[b,o] += sum_cols coef * (w^T G[o,h] w)
  // Gptr wave-uniform -> rows arrive via scalar loads.
  #pragma unroll 1
  for (int o = 0; o < 4; ++o) {
    const float* Gptr = ws + WS_G + (o*27+h)*G_STRIDE;
    float qL = 0.f, qR = 0.f;
    #pragma unroll
    for (int k = 0; k < 22; ++k) {
      const v2f* g2 = (const v2f*)(Gptr + k*24);
      v2f sa = (v2f)(0.f), ra = (v2f)(0.f);
      #pragma unroll
      for (int j = 0; j < 11; ++j) {
        v2f q = g2[j];
        sa += q*wl[j];
        ra += q*wr[j];
      }
      float wLk = wl[k>>1][k&1], wRk = wr[k>>1][k&1];
      qL += wLk*(sa.x + sa.y);
      qR += wRk*(ra.x + ra.y);
    }
    float v = (m <= 10) ? (coefL*qL + coefR*qR) : 0.0f;
    v += __shfl_down(v, 8, 16);
    v += __shfl_down(v, 4, 16);
    v += __shfl_down(v, 2, 16);
    v += __shfl_down(v, 1, 16);
    if (m == 0) {
      if (h == 0) v += ws[WS_CONST + o];
      atomicAdd(out + b*4 + o, v);
    }
  }
}

extern "C" void kernel_launch(void* const* d_in, const int* in_sizes, int n_in,
                              void* d_out, int out_size, void* d_ws, size_t ws_size,
                              hipStream_t stream) {
  const float* x   = (const float*)d_in[0];
  const float* W1  = (const float*)d_in[1];
  const float* W2  = (const float*)d_in[2];
  const float* rm  = (const float*)d_in[3];
  const float* bn  = (const float*)d_in[4];
  const float* cw  = (const float*)d_in[5];
  const float* cb  = (const float*)d_in[6];
  const float* fw  = (const float*)d_in[7];
  const float* fb  = (const float*)d_in[8];
  float* out = (float*)d_out;
  float* ws  = (float*)d_ws;

  hipMemsetAsync(d_out, 0, (size_t)out_size*sizeof(float), stream);
  prep_kernel<<<27, 256, 0, stream>>>(rm, bn, W1, W2, cw, fw, cb, fb, ws);
  main_kernel<<<3456, 64, 0, stream>>>(x, ws, out);
}